// Round 8
// baseline (315.966 us; speedup 1.0000x reference)
//
#include <hip/hip_runtime.h>
#include <hip/hip_bf16.h>

#define NN 100000
#define NE 1600000
#define INDIM 48
#define HID 128
#define K2 256
#define KP 64            // padded K for input projection
#define BN_EPS 1e-5f

// bucket sort parameters: buckets of 128 dst nodes
#define NBUK 782          // ceil(100000/128)
#define BCAP 2816         // mean 2046, sigma~45 -> +17 sigma headroom
#define CHUNK 8192        // edges per phase-1 block
#define NBB 196           // bucket blocks = ceil(NE/CHUNK)
#define NPRJ 316          // proj blocks: NBB+NPRJ = 512 = exactly 2 blocks/CU x 256 CU
#define NGEMM 512         // sage-gemm blocks (grid-stride over MT2 tiles), single occupancy round

#define MT2 ((NN + 127) / 128) // 782 row tiles of 128

typedef short s8v __attribute__((ext_vector_type(8)));
typedef float f4v __attribute__((ext_vector_type(4)));
typedef float f2v __attribute__((ext_vector_type(2)));

__device__ __forceinline__ unsigned short f2bf(float f) {
    __hip_bfloat16 b = __float2bfloat16(f);
    unsigned short u;
    __builtin_memcpy(&u, &b, 2);
    return u;
}
__device__ __forceinline__ float bflo(unsigned u) { return __uint_as_float(u << 16); }
__device__ __forceinline__ float bfhi(unsigned u) { return __uint_as_float(u & 0xffff0000u); }
__device__ __forceinline__ unsigned packbf(float lo, float hi) {
    return (unsigned)f2bf(lo) | ((unsigned)f2bf(hi) << 16);
}

// ---------------- merged phase 1: edge bucket scatter (blocks 0..NBB-1)
//                  + input projection MFMA GEMM (blocks NBB..511) ----------------
// Bucket role is SINGLE-PASS over edges: the counting atomicAdd also yields each edge's
// within-(block,bucket) rank, carried in registers; placement is plain LDS stores.
__global__ __launch_bounds__(512) void k_prep_proj(const int* __restrict__ ei,
                                                   int* __restrict__ bcur,
                                                   unsigned int* __restrict__ bbuf,
                                                   const float* __restrict__ x,
                                                   const float* __restrict__ W1,
                                                   const float* __restrict__ b1,
                                                   unsigned short* __restrict__ Abuf,
                                                   float* __restrict__ colSum,
                                                   float* __restrict__ colSq) {
  union __align__(16) SMem {
    struct {
      int cnt[1024];
      int sc[2][1024];
      int ofs[1024];
      int gbase[1024];
      unsigned int stag[CHUNK];       // 32 KB
      unsigned short sbkt[CHUNK];     // 16 KB
    } p;                              // 68 KB
    struct {
      unsigned short Bsh[HID][KP + 8];  // 18.4 KB
      float redS[8][HID];
      float redQ[8][HID];               // 8 KB
    } g;
  };
  __shared__ SMem sm;
  int tid = threadIdx.x;

  if (blockIdx.x < NBB) {
    // ---- edge bucketing role ----
    int base = blockIdx.x * CHUNK;
    int lim = min(CHUNK, NE - base);
    sm.p.cnt[tid] = 0;
    sm.p.cnt[tid + 512] = 0;
    __syncthreads();
    // pass A: count + remember (tag, bucket, rank) in registers
    unsigned rtag[CHUNK / 512];
    unsigned rbp[CHUNK / 512];        // bucket (10b) << 16 | rank (<8192 fits 16b)
#pragma unroll
    for (int i = 0; i < CHUNK / 512; ++i) {
      int e = i * 512 + tid;
      rtag[i] = 0u;
      rbp[i] = 0xFFFFFFFFu;           // invalid marker
      if (e < lim) {
        int s = ei[base + e];
        int d = ei[NE + base + e];
        s = min(max(s, 0), NN - 1);
        d = min(max(d, 0), NN - 1);
        int b = d >> 7;
        int pos = atomicAdd(&sm.p.cnt[b], 1);
        rtag[i] = (unsigned)s | ((unsigned)(d & 127) << 17);
        rbp[i] = ((unsigned)b << 16) | (unsigned)pos;
      }
    }
    __syncthreads();
    sm.p.sc[0][tid] = sm.p.cnt[tid];
    sm.p.sc[0][tid + 512] = sm.p.cnt[tid + 512];
    __syncthreads();
    int pp = 0;
    for (int d = 1; d < 1024; d <<= 1) {
      int a0 = sm.p.sc[pp][tid];
      int a1 = sm.p.sc[pp][tid + 512];
      if (tid >= d) a0 += sm.p.sc[pp][tid - d];
      a1 += sm.p.sc[pp][tid + 512 - d];   // tid+512 >= d always (d <= 512)
      sm.p.sc[pp ^ 1][tid] = a0;
      sm.p.sc[pp ^ 1][tid + 512] = a1;
      __syncthreads();
      pp ^= 1;
    }
    sm.p.ofs[tid] = sm.p.sc[pp][tid] - sm.p.cnt[tid];
    sm.p.ofs[tid + 512] = sm.p.sc[pp][tid + 512] - sm.p.cnt[tid + 512];
    if (tid < NBUK) sm.p.gbase[tid] = atomicAdd(&bcur[tid], sm.p.cnt[tid]);
    if (tid + 512 < NBUK) sm.p.gbase[tid + 512] = atomicAdd(&bcur[tid + 512], sm.p.cnt[tid + 512]);
    __syncthreads();
    // pass B: place from registers (plain LDS stores, no atomics, no edge re-read)
#pragma unroll
    for (int i = 0; i < CHUNK / 512; ++i) {
      unsigned bp = rbp[i];
      if (bp != 0xFFFFFFFFu) {
        int b = bp >> 16;
        int pos = bp & 0xFFFF;
        int slot = sm.p.ofs[b] + pos;
        sm.p.stag[slot] = rtag[i];
        sm.p.sbkt[slot] = (unsigned short)b;
      }
    }
    __syncthreads();
    // pass C: coalesced flush to global bucket buffer
    for (int s = tid; s < lim; s += 512) {
      int b = sm.p.sbkt[s];
      int off = sm.p.gbase[b] + (s - sm.p.ofs[b]);
      if (off < BCAP) bbuf[(size_t)b * BCAP + off] = sm.p.stag[s];
    }
    return;
  }

  // ---- input projection role: h = bf16(x) @ bf16(W1)^T + b1, 128-row tiles ----
  int bid2 = blockIdx.x - NBB;
  for (int i = tid; i < HID * KP; i += 512) {
    int j = i >> 6, k = i & (KP - 1);
    sm.g.Bsh[j][k] = (k < INDIM) ? f2bf(W1[j * INDIM + k]) : (unsigned short)0;
  }
  __syncthreads();
  int w = tid >> 6, l = tid & 63;
  int m16 = l & 15, q = l >> 4;
  float bcol[8];
#pragma unroll
  for (int nt = 0; nt < 8; ++nt) bcol[nt] = b1[nt * 16 + m16];
  float ssum[8], ssq[8];
#pragma unroll
  for (int nt = 0; nt < 8; ++nt) { ssum[nt] = 0.f; ssq[nt] = 0.f; }
  f4v zero4 = {0.f, 0.f, 0.f, 0.f};
  s8v zero8 = {0, 0, 0, 0, 0, 0, 0, 0};
  for (int tile = bid2; tile < MT2; tile += NPRJ) {
    int row = tile * 128 + w * 16 + m16;
    bool rv = row < NN;
    const float* xr = x + (size_t)row * INDIM;
    f4v acc[8];
#pragma unroll
    for (int nt = 0; nt < 8; ++nt) acc[nt] = zero4;
#pragma unroll
    for (int kt = 0; kt < 2; ++kt) {
      int c0 = kt * 32 + q * 8;
      s8v a = zero8;
      if (rv && c0 < INDIM) {
        float4 v0 = *(const float4*)(xr + c0);
        float4 v1 = *(const float4*)(xr + c0 + 4);
        a[0] = (short)f2bf(v0.x); a[1] = (short)f2bf(v0.y);
        a[2] = (short)f2bf(v0.z); a[3] = (short)f2bf(v0.w);
        a[4] = (short)f2bf(v1.x); a[5] = (short)f2bf(v1.y);
        a[6] = (short)f2bf(v1.z); a[7] = (short)f2bf(v1.w);
      }
#pragma unroll
      for (int nt = 0; nt < 8; ++nt) {
        s8v b = *(const s8v*)(&sm.g.Bsh[nt * 16 + m16][kt * 32 + q * 8]);
        acc[nt] = __builtin_amdgcn_mfma_f32_16x16x32_bf16(a, b, acc[nt], 0, 0, 0);
      }
    }
    int rbase = tile * 128 + w * 16 + q * 4;
#pragma unroll
    for (int nt = 0; nt < 8; ++nt) {
      int col = nt * 16 + m16;
#pragma unroll
      for (int r4 = 0; r4 < 4; ++r4) {
        int rr = rbase + r4;
        if (rr < NN) {
          float v = acc[nt][r4] + bcol[nt];
          Abuf[(size_t)rr * K2 + HID + col] = f2bf(v);
          ssum[nt] += v;
          ssq[nt] = fmaf(v, v, ssq[nt]);
        }
      }
    }
  }
#pragma unroll
  for (int nt = 0; nt < 8; ++nt) {
    float s = ssum[nt], qq = ssq[nt];
    s += __shfl_xor(s, 16);
    s += __shfl_xor(s, 32);
    qq += __shfl_xor(qq, 16);
    qq += __shfl_xor(qq, 32);
    if (q == 0) {
      sm.g.redS[w][nt * 16 + m16] = s;
      sm.g.redQ[w][nt * 16 + m16] = qq;
    }
  }
  __syncthreads();
  if (tid < HID) {
    float s = 0.f, qq = 0.f;
#pragma unroll
    for (int ww = 0; ww < 8; ++ww) { s += sm.g.redS[ww][tid]; qq += sm.g.redQ[ww][tid]; }
    atomicAdd(&colSum[tid], s);
    atomicAdd(&colSq[tid], qq);
  }
}

// ---------------- BN1+ReLU apply: h(bf16)->feat fp32 + bf16 (Abuf) + fp8 (gather table) ----------------
__global__ __launch_bounds__(256) void k_apply(float* __restrict__ feat,
                                               const float* __restrict__ colSum,
                                               const float* __restrict__ colSq,
                                               const float* __restrict__ g1,
                                               const float* __restrict__ be1,
                                               unsigned short* __restrict__ A,
                                               unsigned char* __restrict__ feat8) {
  __shared__ __align__(16) float sa[HID], sb[HID];
  int tid = threadIdx.x;
  if (tid < HID) {
    float mu = colSum[tid] * (1.0f / NN);
    float var = fmaxf(colSq[tid] * (1.0f / NN) - mu * mu, 0.f);
    float a = g1[tid] * rsqrtf(var + BN_EPS);
    sa[tid] = a;
    sb[tid] = be1[tid] - mu * a;
  }
  __syncthreads();
  int i = blockIdx.x * 256 + tid;  // oct index: NN*16
  if (i >= NN * 16) return;
  int r = i >> 4, c8 = (i & 15) << 3;
  unsigned short* ap = A + (size_t)r * K2 + HID + c8;
  uint4 hv = *(const uint4*)ap;
  float4 a0 = *(const float4*)(sa + c8);
  float4 a1 = *(const float4*)(sa + c8 + 4);
  float4 b0 = *(const float4*)(sb + c8);
  float4 b1 = *(const float4*)(sb + c8 + 4);
  float f0 = fmaxf(fmaf(bflo(hv.x), a0.x, b0.x), 0.f);
  float f1 = fmaxf(fmaf(bfhi(hv.x), a0.y, b0.y), 0.f);
  float f2 = fmaxf(fmaf(bflo(hv.y), a0.z, b0.z), 0.f);
  float f3 = fmaxf(fmaf(bfhi(hv.y), a0.w, b0.w), 0.f);
  float f4 = fmaxf(fmaf(bflo(hv.z), a1.x, b1.x), 0.f);
  float f5 = fmaxf(fmaf(bfhi(hv.z), a1.y, b1.y), 0.f);
  float f6 = fmaxf(fmaf(bflo(hv.w), a1.z, b1.z), 0.f);
  float f7 = fmaxf(fmaf(bfhi(hv.w), a1.w, b1.w), 0.f);
  float4 o0 = {f0, f1, f2, f3}, o1 = {f4, f5, f6, f7};
  *(float4*)(feat + (size_t)r * HID + c8) = o0;
  *(float4*)(feat + (size_t)r * HID + c8 + 4) = o1;
  uint4 ob;
  ob.x = packbf(f0, f1);
  ob.y = packbf(f2, f3);
  ob.z = packbf(f4, f5);
  ob.w = packbf(f6, f7);
  *(uint4*)ap = ob;
  // fp8 e4m3 gather copy (HW round): 8 vals -> 2 dwords
  unsigned p0 = __builtin_amdgcn_cvt_pk_fp8_f32(f0, f1, 0u, false);
  p0 = __builtin_amdgcn_cvt_pk_fp8_f32(f2, f3, p0, true);
  unsigned p1 = __builtin_amdgcn_cvt_pk_fp8_f32(f4, f5, 0u, false);
  p1 = __builtin_amdgcn_cvt_pk_fp8_f32(f6, f7, p1, true);
  uint2 o8 = {p0, p1};
  *(uint2*)(feat8 + (size_t)r * HID + c8) = o8;
}

// ---------------- phase 2: per-bucket local CSR (LDS) + fp8 mean aggregation ----------------
__global__ __launch_bounds__(512) void k_bucket_agg(const unsigned int* __restrict__ bbuf,
                                                    const int* __restrict__ bcnt,
                                                    const unsigned char* __restrict__ feat8,
                                                    unsigned short* __restrict__ Abuf) {
  __shared__ unsigned int lcsr[BCAP];   // 11.3 KB
  __shared__ int cnt[128], ofs[128], cur[128];
  __shared__ int sc[2][128];
  int tid = threadIdx.x;
  int b = blockIdx.x;
  int m = min(bcnt[b], BCAP);
  int n0 = b << 7;
  int nb = min(128, NN - n0);
  if (tid < 128) cnt[tid] = 0;
  __syncthreads();
  const unsigned int* bp = bbuf + (size_t)b * BCAP;
  for (int s = tid; s < m; s += 512) {
    unsigned p = bp[s];
    atomicAdd(&cnt[(p >> 17) & 127], 1);
  }
  __syncthreads();
  if (tid < 128) sc[0][tid] = cnt[tid];
  __syncthreads();
  int pp = 0;
  for (int d = 1; d < 128; d <<= 1) {
    if (tid < 128) {
      int v = sc[pp][tid];
      if (tid >= d) v += sc[pp][tid - d];
      sc[pp ^ 1][tid] = v;
    }
    __syncthreads();
    pp ^= 1;
  }
  if (tid < 128) {
    int o = sc[pp][tid] - cnt[tid];
    ofs[tid] = o;
    cur[tid] = o;
  }
  __syncthreads();
  for (int s = tid; s < m; s += 512) {
    unsigned p = bp[s];     // L1-hot second read
    int ld = (p >> 17) & 127;
    int pos = atomicAdd(&cur[ld], 1);
    lcsr[pos] = p & 0x1FFFF;
  }
  __syncthreads();
  int lane = tid & 31;
  int g = tid >> 5;             // 16 groups
  int half = (lane >> 3) & 3;   // which of 4 edges in the iter
  int l8 = lane & 7;            // 16-col chunk within the row
  for (int ln = g; ln < nb; ln += 16) {
    int deg = cnt[ln], beg = ofs[ln];
    float ac[16];
#pragma unroll
    for (int i = 0; i < 16; ++i) ac[i] = 0.f;
#pragma unroll 2
    for (int j = 0; j < deg; j += 4) {
      int idx = j + half;
      uint4 v = {0u, 0u, 0u, 0u};
      if (idx < deg) {
        int s = lcsr[beg + idx];
        v = *(const uint4*)(feat8 + (size_t)s * HID + l8 * 16);
      }
      f2v d;
      d = __builtin_amdgcn_cvt_pk_f32_fp8(v.x, false); ac[0] += d.x;  ac[1] += d.y;
      d = __builtin_amdgcn_cvt_pk_f32_fp8(v.x, true);  ac[2] += d.x;  ac[3] += d.y;
      d = __builtin_amdgcn_cvt_pk_f32_fp8(v.y, false); ac[4] += d.x;  ac[5] += d.y;
      d = __builtin_amdgcn_cvt_pk_f32_fp8(v.y, true);  ac[6] += d.x;  ac[7] += d.y;
      d = __builtin_amdgcn_cvt_pk_f32_fp8(v.z, false); ac[8] += d.x;  ac[9] += d.y;
      d = __builtin_amdgcn_cvt_pk_f32_fp8(v.z, true);  ac[10] += d.x; ac[11] += d.y;
      d = __builtin_amdgcn_cvt_pk_f32_fp8(v.w, false); ac[12] += d.x; ac[13] += d.y;
      d = __builtin_amdgcn_cvt_pk_f32_fp8(v.w, true);  ac[14] += d.x; ac[15] += d.y;
    }
#pragma unroll
    for (int i = 0; i < 16; ++i) {
      ac[i] += __shfl_xor(ac[i], 8);
      ac[i] += __shfl_xor(ac[i], 16);
    }
    if (half == 0) {
      float inv = 1.f / fmaxf((float)deg, 1.f);
      uint4 o0, o1;
      o0.x = packbf(ac[0] * inv, ac[1] * inv);
      o0.y = packbf(ac[2] * inv, ac[3] * inv);
      o0.z = packbf(ac[4] * inv, ac[5] * inv);
      o0.w = packbf(ac[6] * inv, ac[7] * inv);
      o1.x = packbf(ac[8] * inv, ac[9] * inv);
      o1.y = packbf(ac[10] * inv, ac[11] * inv);
      o1.z = packbf(ac[12] * inv, ac[13] * inv);
      o1.w = packbf(ac[14] * inv, ac[15] * inv);
      unsigned short* op = Abuf + (size_t)(n0 + ln) * K2 + l8 * 16;
      *(uint4*)op = o0;
      *(uint4*)(op + 8) = o1;
    }
  }
}

// ---------------- MFMA GEMM: sage = A[N,256] @ [Wl|Wr]^T + bl ----------------
// Grid-stride 512 blocks (all co-resident at 2/CU): B cast hoisted (once per block,
// not per tile); BN2 stats accumulated in registers across tiles, one atomic per block.
__global__ __launch_bounds__(512) void k_gemm(
    const unsigned short* __restrict__ A,
    const float* __restrict__ Wl, const float* __restrict__ Wr,
    const float* __restrict__ bl, unsigned short* __restrict__ sageb,
    float* __restrict__ colSum, float* __restrict__ colSq) {
  __shared__ __align__(16) unsigned short Bsh[HID][264];  // 128 cols x 256 k, +8 pad: 67.6 KB
  __shared__ float redS[8][HID], redQ[8][HID];            // 8 KB
  int tid = threadIdx.x;
  // cast Wl|Wr fp32 -> bf16 LDS B-tile (once per block)
  for (int i4 = tid; i4 < HID * K2 / 4; i4 += 512) {
    int i = i4 << 2;
    int j = i >> 8, k = i & (K2 - 1);
    const float* src = (k < HID) ? (Wl + j * HID + k) : (Wr + j * HID + (k - HID));
    float4 v = *(const float4*)src;
    uint2 u;
    u.x = packbf(v.x, v.y);
    u.y = packbf(v.z, v.w);
    *(uint2*)&Bsh[j][k] = u;
  }
  __syncthreads();
  int w = tid >> 6, l = tid & 63;
  int m16 = l & 15, q = l >> 4;
  float bcol[8];
#pragma unroll
  for (int nt = 0; nt < 8; ++nt) bcol[nt] = bl[nt * 16 + m16];
  f4v zero4 = {0.f, 0.f, 0.f, 0.f};
  s8v zero8 = {0, 0, 0, 0, 0, 0, 0, 0};
  float ssum[8], ssq[8];
#pragma unroll
  for (int nt = 0; nt < 8; ++nt) { ssum[nt] = 0.f; ssq[nt] = 0.f; }
  for (int tile = blockIdx.x; tile < MT2; tile += NGEMM) {
    int row = tile * 128 + w * 16 + m16;
    bool rv = row < NN;
    f4v acc[8];
#pragma unroll
    for (int nt = 0; nt < 8; ++nt) acc[nt] = zero4;
#pragma unroll
    for (int kt = 0; kt < 8; ++kt) {
      s8v a = zero8;
      if (rv) a = *(const s8v*)(A + (size_t)row * K2 + kt * 32 + q * 8);
#pragma unroll
      for (int nt = 0; nt < 8; ++nt) {
        s8v bfr = *(const s8v*)(&Bsh[nt * 16 + m16][kt * 32 + q * 8]);
        acc[nt] = __builtin_amdgcn_mfma_f32_16x16x32_bf16(a, bfr, acc[nt], 0, 0, 0);
      }
    }
    int rbase = tile * 128 + w * 16 + q * 4;
#pragma unroll
    for (int nt = 0; nt < 8; ++nt) {
      int col = nt * 16 + m16;
#pragma unroll
      for (int r4 = 0; r4 < 4; ++r4) {
        int rr = rbase + r4;
        if (rr < NN) {
          float v = acc[nt][r4] + bcol[nt];
          sageb[(size_t)rr * HID + col] = f2bf(v);
          ssum[nt] += v;
          ssq[nt] = fmaf(v, v, ssq[nt]);
        }
      }
    }
  }
#pragma unroll
  for (int nt = 0; nt < 8; ++nt) {
    float s = ssum[nt], qq = ssq[nt];
    s += __shfl_xor(s, 16);
    s += __shfl_xor(s, 32);
    qq += __shfl_xor(qq, 16);
    qq += __shfl_xor(qq, 32);
    if (q == 0) {
      redS[w][nt * 16 + m16] = s;
      redQ[w][nt * 16 + m16] = qq;
    }
  }
  __syncthreads();
  if (tid < HID) {
    float s = 0.f, qq = 0.f;
#pragma unroll
    for (int ww = 0; ww < 8; ++ww) { s += redS[ww][tid]; qq += redQ[ww][tid]; }
    atomicAdd(&colSum[tid], s);
    atomicAdd(&colSq[tid], qq);
  }
}

// ---------------- BN2 apply (finalize folded): read bf16 sage, write fp32 d_out ----------------
__global__ __launch_bounds__(256) void k_bn_apply(const unsigned short* __restrict__ sageb,
                                                  float* __restrict__ out,
                                                  const float* __restrict__ colSum,
                                                  const float* __restrict__ colSq,
                                                  const float* __restrict__ g2,
                                                  const float* __restrict__ be2) {
  __shared__ __align__(16) float sa[HID], sb[HID];
  int tid = threadIdx.x;
  if (tid < HID) {
    float mu = colSum[tid] * (1.0f / NN);
    float var = fmaxf(colSq[tid] * (1.0f / NN) - mu * mu, 0.f);
    float a = g2[tid] * rsqrtf(var + BN_EPS);
    sa[tid] = a;
    sb[tid] = be2[tid] - mu * a;
  }
  __syncthreads();
  int i = blockIdx.x * 256 + tid;  // oct index: NN*16
  if (i >= NN * 16) return;
  int r = i >> 4, c8 = (i & 15) << 3;
  uint4 sv = *(const uint4*)(sageb + (size_t)r * HID + c8);
  float4 a0 = *(const float4*)(sa + c8);
  float4 a1 = *(const float4*)(sa + c8 + 4);
  float4 b0 = *(const float4*)(sb + c8);
  float4 b1 = *(const float4*)(sb + c8 + 4);
  float4 o0, o1;
  o0.x = fmaf(bflo(sv.x), a0.x, b0.x);
  o0.y = fmaf(bfhi(sv.x), a0.y, b0.y);
  o0.z = fmaf(bflo(sv.y), a0.z, b0.z);
  o0.w = fmaf(bfhi(sv.y), a0.w, b0.w);
  o1.x = fmaf(bflo(sv.z), a1.x, b1.x);
  o1.y = fmaf(bfhi(sv.z), a1.y, b1.y);
  o1.z = fmaf(bflo(sv.w), a1.z, b1.z);
  o1.w = fmaf(bfhi(sv.w), a1.w, b1.w);
  *(float4*)(out + (size_t)r * HID + c8) = o0;
  *(float4*)(out + (size_t)r * HID + c8 + 4) = o1;
}

extern "C" void kernel_launch(void* const* d_in, const int* in_sizes, int n_in,
                              void* d_out, int out_size, void* d_ws, size_t ws_size,
                              hipStream_t stream) {
  const float* x   = (const float*)d_in[0];
  const int*   ei  = (const int*)d_in[1];
  const float* W1  = (const float*)d_in[2];
  const float* b1  = (const float*)d_in[3];
  const float* g1  = (const float*)d_in[4];
  const float* be1 = (const float*)d_in[5];
  const float* Wl  = (const float*)d_in[6];
  const float* bl  = (const float*)d_in[7];
  const float* Wr  = (const float*)d_in[8];
  const float* g2  = (const float*)d_in[9];
  const float* be2 = (const float*)d_in[10];

  float* feat_out = (float*)d_out;                      // output 0: feat fp32
  float* out2     = (float*)d_out + (size_t)NN * HID;   // output 1: BN2(sage) fp32

  size_t off = 0;
  auto alloc = [&](size_t bytes) -> void* {
    void* p = (char*)d_ws + off;
    off += (bytes + 255) & ~(size_t)255;
    return p;
  };
  // stats + bcur first and contiguous: one small memset clears all
  float*          stats = (float*)alloc(4 * HID * 4);                    // 2048 B
  int*            bcur  = (int*)alloc((size_t)NBUK * 4);                 // directly after stats
  unsigned short* Abuf  = (unsigned short*)alloc((size_t)NN * K2 * 2);   // [NN][256] bf16: agg|feat
  unsigned char*  feat8 = (unsigned char*)alloc((size_t)NN * HID);       // fp8 e4m3 gather table
  unsigned short* sageb = (unsigned short*)alloc((size_t)NN * HID * 2);  // bf16 sage scratch
  unsigned int*   bbuf  = (unsigned int*)alloc((size_t)NBUK * BCAP * 4);
  float* colSum1 = stats;
  float* colSq1  = stats + HID;
  float* colSum2 = stats + 2 * HID;
  float* colSq2  = stats + 3 * HID;

  hipMemsetAsync(stats, 0, 4 * HID * 4 + (size_t)NBUK * 4, stream);
  k_prep_proj<<<NBB + NPRJ, 512, 0, stream>>>(ei, bcur, bbuf, x, W1, b1, Abuf, colSum1, colSq1);
  k_apply<<<(NN * 16 + 255) / 256, 256, 0, stream>>>(feat_out, colSum1, colSq1, g1, be1, Abuf, feat8);
  k_bucket_agg<<<NBUK, 512, 0, stream>>>(bbuf, bcur, feat8, Abuf);
  k_gemm<<<NGEMM, 512, 0, stream>>>(Abuf, Wl, Wr, bl, sageb, colSum2, colSq2);
  k_bn_apply<<<(NN * 16 + 255) / 256, 256, 0, stream>>>(sageb, out2, colSum2, colSq2, g2, be2);
}

// Round 9
// 279.049 us; speedup vs baseline: 1.1323x; 1.1323x over previous
//
#include <hip/hip_runtime.h>
#include <hip/hip_bf16.h>

#define NN 100000
#define NE 1600000
#define INDIM 48
#define HID 128
#define K2 256
#define KP 64            // padded K for input projection
#define BN_EPS 1e-5f

// bucket sort parameters: buckets of 128 dst nodes
#define NBUK 782          // ceil(100000/128)
#define BCAP 2816         // mean 2046, sigma~45 -> +17 sigma headroom
#define CHUNK 8192        // edges per phase-1 block
#define NBB 196           // bucket blocks = ceil(NE/CHUNK)
#define NPRJ 320          // proj-gemm blocks riding on the same grid

#define MT2 ((NN + 127) / 128) // 782 row tiles of 128

#define BSTR 264          // gemm B-tile row stride (shorts), 16B-aligned
#define PSTR 72           // proj B-tile row stride (shorts), 16B-aligned

typedef short s8v __attribute__((ext_vector_type(8)));
typedef float f4v __attribute__((ext_vector_type(4)));
typedef float f2v __attribute__((ext_vector_type(2)));

__device__ __forceinline__ unsigned short f2bf(float f) {
    __hip_bfloat16 b = __float2bfloat16(f);
    unsigned short u;
    __builtin_memcpy(&u, &b, 2);
    return u;
}
__device__ __forceinline__ float bflo(unsigned u) { return __uint_as_float(u << 16); }
__device__ __forceinline__ float bfhi(unsigned u) { return __uint_as_float(u & 0xffff0000u); }
__device__ __forceinline__ unsigned packbf(float lo, float hi) {
    return (unsigned)f2bf(lo) | ((unsigned)f2bf(hi) << 16);
}

// ---------------- merged phase 1: edge bucket scatter (blocks 0..NBB-1)
//                  + input projection MFMA GEMM (blocks NBB..NBB+NPRJ-1) ----------------
// Bucket role is SINGLE-PASS over edges (count atomicAdd doubles as rank; placement via
// plain LDS stores). Proj role uses lane->col remap (col = m16*8+nt) so the h-store is a
// single uint4 per row per lane (full 64B sectors, no RMW write amplification); the B-tile
// is XOR-swizzled (byte ^= ((row>>3)&7)<<4) to kill the 8-row-stride bank conflict.
__global__ __launch_bounds__(512) void k_prep_proj(const int* __restrict__ ei,
                                                   int* __restrict__ bcur,
                                                   unsigned int* __restrict__ bbuf,
                                                   const float* __restrict__ x,
                                                   const float* __restrict__ W1,
                                                   const float* __restrict__ b1,
                                                   unsigned short* __restrict__ Abuf,
                                                   float* __restrict__ colSum,
                                                   float* __restrict__ colSq) {
  union __align__(16) SMem {
    struct {
      int cnt[1024];
      int sc[2][1024];
      int ofs[1024];
      int gbase[1024];
      unsigned int stag[CHUNK];       // 32 KB
      unsigned short sbkt[CHUNK];     // 16 KB
    } p;                              // 68 KB
    struct {
      unsigned short Bsh[HID * PSTR];   // 18.4 KB (swizzled)
      float redS[8][HID];
      float redQ[8][HID];               // 8 KB
    } g;
  };
  __shared__ SMem sm;
  int tid = threadIdx.x;

  if (blockIdx.x < NBB) {
    // ---- edge bucketing role ----
    int base = blockIdx.x * CHUNK;
    int lim = min(CHUNK, NE - base);
    sm.p.cnt[tid] = 0;
    sm.p.cnt[tid + 512] = 0;
    __syncthreads();
    // pass A: count + remember (tag, bucket, rank) in registers
    unsigned rtag[CHUNK / 512];
    unsigned rbp[CHUNK / 512];        // bucket (10b) << 16 | rank (<8192 fits 16b)
#pragma unroll
    for (int i = 0; i < CHUNK / 512; ++i) {
      int e = i * 512 + tid;
      rtag[i] = 0u;
      rbp[i] = 0xFFFFFFFFu;           // invalid marker
      if (e < lim) {
        int s = ei[base + e];
        int d = ei[NE + base + e];
        s = min(max(s, 0), NN - 1);
        d = min(max(d, 0), NN - 1);
        int b = d >> 7;
        int pos = atomicAdd(&sm.p.cnt[b], 1);
        rtag[i] = (unsigned)s | ((unsigned)(d & 127) << 17);
        rbp[i] = ((unsigned)b << 16) | (unsigned)pos;
      }
    }
    __syncthreads();
    sm.p.sc[0][tid] = sm.p.cnt[tid];
    sm.p.sc[0][tid + 512] = sm.p.cnt[tid + 512];
    __syncthreads();
    int pp = 0;
    for (int d = 1; d < 1024; d <<= 1) {
      int a0 = sm.p.sc[pp][tid];
      int a1 = sm.p.sc[pp][tid + 512];
      if (tid >= d) a0 += sm.p.sc[pp][tid - d];
      a1 += sm.p.sc[pp][tid + 512 - d];   // tid+512 >= d always (d <= 512)
      sm.p.sc[pp ^ 1][tid] = a0;
      sm.p.sc[pp ^ 1][tid + 512] = a1;
      __syncthreads();
      pp ^= 1;
    }
    sm.p.ofs[tid] = sm.p.sc[pp][tid] - sm.p.cnt[tid];
    sm.p.ofs[tid + 512] = sm.p.sc[pp][tid + 512] - sm.p.cnt[tid + 512];
    if (tid < NBUK) sm.p.gbase[tid] = atomicAdd(&bcur[tid], sm.p.cnt[tid]);
    if (tid + 512 < NBUK) sm.p.gbase[tid + 512] = atomicAdd(&bcur[tid + 512], sm.p.cnt[tid + 512]);
    __syncthreads();
    // pass B: place from registers (plain LDS stores, no atomics, no edge re-read)
#pragma unroll
    for (int i = 0; i < CHUNK / 512; ++i) {
      unsigned bp = rbp[i];
      if (bp != 0xFFFFFFFFu) {
        int b = bp >> 16;
        int pos = bp & 0xFFFF;
        int slot = sm.p.ofs[b] + pos;
        sm.p.stag[slot] = rtag[i];
        sm.p.sbkt[slot] = (unsigned short)b;
      }
    }
    __syncthreads();
    // pass C: coalesced flush to global bucket buffer
    for (int s = tid; s < lim; s += 512) {
      int b = sm.p.sbkt[s];
      int off = sm.p.gbase[b] + (s - sm.p.ofs[b]);
      if (off < BCAP) bbuf[(size_t)b * BCAP + off] = sm.p.stag[s];
    }
    return;
  }

  // ---- input projection role: h = bf16(x) @ bf16(W1)^T + b1, 128-row tiles ----
  int bid2 = blockIdx.x - NBB;
  for (int i = tid; i < HID * KP; i += 512) {
    int j = i >> 6, k = i & (KP - 1);
    unsigned short val = (k < INDIM) ? f2bf(W1[j * INDIM + k]) : (unsigned short)0;
    unsigned boff = (unsigned)(k * 2) ^ ((((unsigned)j >> 3) & 7u) << 4);
    *(unsigned short*)((char*)&sm.g.Bsh[(size_t)j * PSTR] + boff) = val;
  }
  __syncthreads();
  int w = tid >> 6, l = tid & 63;
  int m16 = l & 15, q = l >> 4;
  unsigned sw = ((unsigned)m16 & 7u) << 4;   // read-side swizzle key: (row>>3)&7 == m16&7
  float bcol[8];
#pragma unroll
  for (int nt = 0; nt < 8; ++nt) bcol[nt] = b1[m16 * 8 + nt];   // col = m16*8+nt
  float ssum[8], ssq[8];
#pragma unroll
  for (int nt = 0; nt < 8; ++nt) { ssum[nt] = 0.f; ssq[nt] = 0.f; }
  f4v zero4 = {0.f, 0.f, 0.f, 0.f};
  s8v zero8 = {0, 0, 0, 0, 0, 0, 0, 0};
  for (int tile = bid2; tile < MT2; tile += NPRJ) {
    int row = tile * 128 + w * 16 + m16;
    bool rv = row < NN;
    const float* xr = x + (size_t)row * INDIM;
    f4v acc[8];
#pragma unroll
    for (int nt = 0; nt < 8; ++nt) acc[nt] = zero4;
#pragma unroll
    for (int kt = 0; kt < 2; ++kt) {
      int c0 = kt * 32 + q * 8;
      s8v a = zero8;
      if (rv && c0 < INDIM) {
        float4 v0 = *(const float4*)(xr + c0);
        float4 v1 = *(const float4*)(xr + c0 + 4);
        a[0] = (short)f2bf(v0.x); a[1] = (short)f2bf(v0.y);
        a[2] = (short)f2bf(v0.z); a[3] = (short)f2bf(v0.w);
        a[4] = (short)f2bf(v1.x); a[5] = (short)f2bf(v1.y);
        a[6] = (short)f2bf(v1.z); a[7] = (short)f2bf(v1.w);
      }
      unsigned base = (unsigned)(kt * 64 + q * 16) ^ sw;
#pragma unroll
      for (int nt = 0; nt < 8; ++nt) {
        int brow = m16 * 8 + nt;
        s8v b = *(const s8v*)((const char*)&sm.g.Bsh[(size_t)brow * PSTR] + base);
        acc[nt] = __builtin_amdgcn_mfma_f32_16x16x32_bf16(a, b, acc[nt], 0, 0, 0);
      }
    }
    int rbase = tile * 128 + w * 16 + q * 4;
#pragma unroll
    for (int r4 = 0; r4 < 4; ++r4) {
      int rr = rbase + r4;
      if (rr < NN) {
        float v0 = acc[0][r4] + bcol[0], v1 = acc[1][r4] + bcol[1];
        float v2 = acc[2][r4] + bcol[2], v3 = acc[3][r4] + bcol[3];
        float v4 = acc[4][r4] + bcol[4], v5 = acc[5][r4] + bcol[5];
        float v6 = acc[6][r4] + bcol[6], v7 = acc[7][r4] + bcol[7];
        uint4 o;
        o.x = packbf(v0, v1); o.y = packbf(v2, v3);
        o.z = packbf(v4, v5); o.w = packbf(v6, v7);
        *(uint4*)(Abuf + (size_t)rr * K2 + HID + m16 * 8) = o;
        ssum[0] += v0; ssq[0] = fmaf(v0, v0, ssq[0]);
        ssum[1] += v1; ssq[1] = fmaf(v1, v1, ssq[1]);
        ssum[2] += v2; ssq[2] = fmaf(v2, v2, ssq[2]);
        ssum[3] += v3; ssq[3] = fmaf(v3, v3, ssq[3]);
        ssum[4] += v4; ssq[4] = fmaf(v4, v4, ssq[4]);
        ssum[5] += v5; ssq[5] = fmaf(v5, v5, ssq[5]);
        ssum[6] += v6; ssq[6] = fmaf(v6, v6, ssq[6]);
        ssum[7] += v7; ssq[7] = fmaf(v7, v7, ssq[7]);
      }
    }
  }
#pragma unroll
  for (int nt = 0; nt < 8; ++nt) {
    float s = ssum[nt], qq = ssq[nt];
    s += __shfl_xor(s, 16);
    s += __shfl_xor(s, 32);
    qq += __shfl_xor(qq, 16);
    qq += __shfl_xor(qq, 32);
    if (q == 0) {
      sm.g.redS[w][m16 * 8 + nt] = s;
      sm.g.redQ[w][m16 * 8 + nt] = qq;
    }
  }
  __syncthreads();
  if (tid < HID) {
    float s = 0.f, qq = 0.f;
#pragma unroll
    for (int ww = 0; ww < 8; ++ww) { s += sm.g.redS[ww][tid]; qq += sm.g.redQ[ww][tid]; }
    atomicAdd(&colSum[tid], s);
    atomicAdd(&colSq[tid], qq);
  }
}

// ---------------- BN1+ReLU apply: h(bf16)->feat fp32 + bf16 (Abuf) + fp8 (gather table) ----------------
__global__ __launch_bounds__(256) void k_apply(float* __restrict__ feat,
                                               const float* __restrict__ colSum,
                                               const float* __restrict__ colSq,
                                               const float* __restrict__ g1,
                                               const float* __restrict__ be1,
                                               unsigned short* __restrict__ A,
                                               unsigned char* __restrict__ feat8) {
  __shared__ __align__(16) float sa[HID], sb[HID];
  int tid = threadIdx.x;
  if (tid < HID) {
    float mu = colSum[tid] * (1.0f / NN);
    float var = fmaxf(colSq[tid] * (1.0f / NN) - mu * mu, 0.f);
    float a = g1[tid] * rsqrtf(var + BN_EPS);
    sa[tid] = a;
    sb[tid] = be1[tid] - mu * a;
  }
  __syncthreads();
  int i = blockIdx.x * 256 + tid;  // oct index: NN*16
  if (i >= NN * 16) return;
  int r = i >> 4, c8 = (i & 15) << 3;
  unsigned short* ap = A + (size_t)r * K2 + HID + c8;
  uint4 hv = *(const uint4*)ap;
  float4 a0 = *(const float4*)(sa + c8);
  float4 a1 = *(const float4*)(sa + c8 + 4);
  float4 b0 = *(const float4*)(sb + c8);
  float4 b1 = *(const float4*)(sb + c8 + 4);
  float f0 = fmaxf(fmaf(bflo(hv.x), a0.x, b0.x), 0.f);
  float f1 = fmaxf(fmaf(bfhi(hv.x), a0.y, b0.y), 0.f);
  float f2 = fmaxf(fmaf(bflo(hv.y), a0.z, b0.z), 0.f);
  float f3 = fmaxf(fmaf(bfhi(hv.y), a0.w, b0.w), 0.f);
  float f4 = fmaxf(fmaf(bflo(hv.z), a1.x, b1.x), 0.f);
  float f5 = fmaxf(fmaf(bfhi(hv.z), a1.y, b1.y), 0.f);
  float f6 = fmaxf(fmaf(bflo(hv.w), a1.z, b1.z), 0.f);
  float f7 = fmaxf(fmaf(bfhi(hv.w), a1.w, b1.w), 0.f);
  float4 o0 = {f0, f1, f2, f3}, o1 = {f4, f5, f6, f7};
  *(float4*)(feat + (size_t)r * HID + c8) = o0;
  *(float4*)(feat + (size_t)r * HID + c8 + 4) = o1;
  uint4 ob;
  ob.x = packbf(f0, f1);
  ob.y = packbf(f2, f3);
  ob.z = packbf(f4, f5);
  ob.w = packbf(f6, f7);
  *(uint4*)ap = ob;
  // fp8 e4m3 gather copy (HW round): 8 vals -> 2 dwords
  unsigned p0 = __builtin_amdgcn_cvt_pk_fp8_f32(f0, f1, 0u, false);
  p0 = __builtin_amdgcn_cvt_pk_fp8_f32(f2, f3, p0, true);
  unsigned p1 = __builtin_amdgcn_cvt_pk_fp8_f32(f4, f5, 0u, false);
  p1 = __builtin_amdgcn_cvt_pk_fp8_f32(f6, f7, p1, true);
  uint2 o8 = {p0, p1};
  *(uint2*)(feat8 + (size_t)r * HID + c8) = o8;
}

// ---------------- phase 2: per-bucket local CSR (LDS) + fp8 mean aggregation ----------------
__global__ __launch_bounds__(512) void k_bucket_agg(const unsigned int* __restrict__ bbuf,
                                                    const int* __restrict__ bcnt,
                                                    const unsigned char* __restrict__ feat8,
                                                    unsigned short* __restrict__ Abuf) {
  __shared__ unsigned int lcsr[BCAP];   // 11.3 KB
  __shared__ int cnt[128], ofs[128], cur[128];
  __shared__ int sc[2][128];
  int tid = threadIdx.x;
  int b = blockIdx.x;
  int m = min(bcnt[b], BCAP);
  int n0 = b << 7;
  int nb = min(128, NN - n0);
  if (tid < 128) cnt[tid] = 0;
  __syncthreads();
  const unsigned int* bp = bbuf + (size_t)b * BCAP;
  for (int s = tid; s < m; s += 512) {
    unsigned p = bp[s];
    atomicAdd(&cnt[(p >> 17) & 127], 1);
  }
  __syncthreads();
  if (tid < 128) sc[0][tid] = cnt[tid];
  __syncthreads();
  int pp = 0;
  for (int d = 1; d < 128; d <<= 1) {
    if (tid < 128) {
      int v = sc[pp][tid];
      if (tid >= d) v += sc[pp][tid - d];
      sc[pp ^ 1][tid] = v;
    }
    __syncthreads();
    pp ^= 1;
  }
  if (tid < 128) {
    int o = sc[pp][tid] - cnt[tid];
    ofs[tid] = o;
    cur[tid] = o;
  }
  __syncthreads();
  for (int s = tid; s < m; s += 512) {
    unsigned p = bp[s];     // L1-hot second read
    int ld = (p >> 17) & 127;
    int pos = atomicAdd(&cur[ld], 1);
    lcsr[pos] = p & 0x1FFFF;
  }
  __syncthreads();
  int lane = tid & 31;
  int g = tid >> 5;             // 16 groups
  int half = (lane >> 3) & 3;   // which of 4 edges in the iter
  int l8 = lane & 7;            // 16-col chunk within the row
  for (int ln = g; ln < nb; ln += 16) {
    int deg = cnt[ln], beg = ofs[ln];
    float ac[16];
#pragma unroll
    for (int i = 0; i < 16; ++i) ac[i] = 0.f;
#pragma unroll 2
    for (int j = 0; j < deg; j += 4) {
      int idx = j + half;
      uint4 v = {0u, 0u, 0u, 0u};
      if (idx < deg) {
        int s = lcsr[beg + idx];
        v = *(const uint4*)(feat8 + (size_t)s * HID + l8 * 16);
      }
      f2v d;
      d = __builtin_amdgcn_cvt_pk_f32_fp8(v.x, false); ac[0] += d.x;  ac[1] += d.y;
      d = __builtin_amdgcn_cvt_pk_f32_fp8(v.x, true);  ac[2] += d.x;  ac[3] += d.y;
      d = __builtin_amdgcn_cvt_pk_f32_fp8(v.y, false); ac[4] += d.x;  ac[5] += d.y;
      d = __builtin_amdgcn_cvt_pk_f32_fp8(v.y, true);  ac[6] += d.x;  ac[7] += d.y;
      d = __builtin_amdgcn_cvt_pk_f32_fp8(v.z, false); ac[8] += d.x;  ac[9] += d.y;
      d = __builtin_amdgcn_cvt_pk_f32_fp8(v.z, true);  ac[10] += d.x; ac[11] += d.y;
      d = __builtin_amdgcn_cvt_pk_f32_fp8(v.w, false); ac[12] += d.x; ac[13] += d.y;
      d = __builtin_amdgcn_cvt_pk_f32_fp8(v.w, true);  ac[14] += d.x; ac[15] += d.y;
    }
#pragma unroll
    for (int i = 0; i < 16; ++i) {
      ac[i] += __shfl_xor(ac[i], 8);
      ac[i] += __shfl_xor(ac[i], 16);
    }
    if (half == 0) {
      float inv = 1.f / fmaxf((float)deg, 1.f);
      uint4 o0, o1;
      o0.x = packbf(ac[0] * inv, ac[1] * inv);
      o0.y = packbf(ac[2] * inv, ac[3] * inv);
      o0.z = packbf(ac[4] * inv, ac[5] * inv);
      o0.w = packbf(ac[6] * inv, ac[7] * inv);
      o1.x = packbf(ac[8] * inv, ac[9] * inv);
      o1.y = packbf(ac[10] * inv, ac[11] * inv);
      o1.z = packbf(ac[12] * inv, ac[13] * inv);
      o1.w = packbf(ac[14] * inv, ac[15] * inv);
      unsigned short* op = Abuf + (size_t)(n0 + ln) * K2 + l8 * 16;
      *(uint4*)op = o0;
      *(uint4*)(op + 8) = o1;
    }
  }
}

// ---------------- MFMA GEMM: sage = A[N,256] @ [Wl|Wr]^T + bl ----------------
// 128x128 tile per block (782 blocks). Lane->col remap (col = m16*8+nt) => sageb store is
// one uint4 per row per lane (full 64B sectors). B-tile XOR-swizzled against the
// 8-row-stride bank conflict the remap would otherwise cause.
__global__ __launch_bounds__(512) void k_gemm(
    const unsigned short* __restrict__ A,
    const float* __restrict__ Wl, const float* __restrict__ Wr,
    const float* __restrict__ bl, unsigned short* __restrict__ sageb,
    float* __restrict__ colSum, float* __restrict__ colSq) {
  __shared__ __align__(16) unsigned short Bsh[HID * BSTR];  // 67.6 KB (swizzled)
  __shared__ float redS[8][HID], redQ[8][HID];              // 8 KB
  int tid = threadIdx.x;
  // cast Wl|Wr fp32 -> bf16 swizzled LDS B-tile
  for (int i4 = tid; i4 < HID * K2 / 4; i4 += 512) {
    int i = i4 << 2;
    int j = i >> 8, k = i & (K2 - 1);
    const float* src = (k < HID) ? (Wl + j * HID + k) : (Wr + j * HID + (k - HID));
    float4 v = *(const float4*)src;
    uint2 u;
    u.x = packbf(v.x, v.y);
    u.y = packbf(v.z, v.w);
    unsigned boff = (unsigned)(k * 2) ^ ((((unsigned)j >> 3) & 7u) << 4);
    *(uint2*)((char*)&Bsh[(size_t)j * BSTR] + boff) = u;
  }
  __syncthreads();
  int w = tid >> 6, l = tid & 63;
  int m16 = l & 15, q = l >> 4;
  unsigned sw = ((unsigned)m16 & 7u) << 4;   // read key: (row>>3)&7 == m16&7 (row = m16*8+nt)
  int tile = blockIdx.x;
  int row = tile * 128 + w * 16 + m16;
  bool rv = row < NN;
  f4v zero4 = {0.f, 0.f, 0.f, 0.f};
  s8v zero8 = {0, 0, 0, 0, 0, 0, 0, 0};
  float bcol[8];
#pragma unroll
  for (int nt = 0; nt < 8; ++nt) bcol[nt] = bl[m16 * 8 + nt];   // col = m16*8+nt
  f4v acc[8];
#pragma unroll
  for (int nt = 0; nt < 8; ++nt) acc[nt] = zero4;
#pragma unroll
  for (int kt = 0; kt < 8; ++kt) {
    s8v a = zero8;
    if (rv) a = *(const s8v*)(A + (size_t)row * K2 + kt * 32 + q * 8);
    unsigned base = (unsigned)(kt * 64 + q * 16) ^ sw;
#pragma unroll
    for (int nt = 0; nt < 8; ++nt) {
      int brow = m16 * 8 + nt;
      s8v bfr = *(const s8v*)((const char*)&Bsh[(size_t)brow * BSTR] + base);
      acc[nt] = __builtin_amdgcn_mfma_f32_16x16x32_bf16(a, bfr, acc[nt], 0, 0, 0);
    }
  }
  int rbase = tile * 128 + w * 16 + q * 4;
  float ssum[8], ssq[8];
#pragma unroll
  for (int nt = 0; nt < 8; ++nt) { ssum[nt] = 0.f; ssq[nt] = 0.f; }
#pragma unroll
  for (int r4 = 0; r4 < 4; ++r4) {
    int rr = rbase + r4;
    if (rr < NN) {
      float v0 = acc[0][r4] + bcol[0], v1 = acc[1][r4] + bcol[1];
      float v2 = acc[2][r4] + bcol[2], v3 = acc[3][r4] + bcol[3];
      float v4 = acc[4][r4] + bcol[4], v5 = acc[5][r4] + bcol[5];
      float v6 = acc[6][r4] + bcol[6], v7 = acc[7][r4] + bcol[7];
      uint4 o;
      o.x = packbf(v0, v1); o.y = packbf(v2, v3);
      o.z = packbf(v4, v5); o.w = packbf(v6, v7);
      *(uint4*)(sageb + (size_t)rr * HID + m16 * 8) = o;
      ssum[0] += v0; ssq[0] = fmaf(v0, v0, ssq[0]);
      ssum[1] += v1; ssq[1] = fmaf(v1, v1, ssq[1]);
      ssum[2] += v2; ssq[2] = fmaf(v2, v2, ssq[2]);
      ssum[3] += v3; ssq[3] = fmaf(v3, v3, ssq[3]);
      ssum[4] += v4; ssq[4] = fmaf(v4, v4, ssq[4]);
      ssum[5] += v5; ssq[5] = fmaf(v5, v5, ssq[5]);
      ssum[6] += v6; ssq[6] = fmaf(v6, v6, ssq[6]);
      ssum[7] += v7; ssq[7] = fmaf(v7, v7, ssq[7]);
    }
  }
#pragma unroll
  for (int nt = 0; nt < 8; ++nt) {
    float s = ssum[nt], qq = ssq[nt];
    s += __shfl_xor(s, 16);
    s += __shfl_xor(s, 32);
    qq += __shfl_xor(qq, 16);
    qq += __shfl_xor(qq, 32);
    if (q == 0) {
      redS[w][m16 * 8 + nt] = s;
      redQ[w][m16 * 8 + nt] = qq;
    }
  }
  __syncthreads();
  if (tid < HID) {
    float s = 0.f, qq = 0.f;
#pragma unroll
    for (int ww = 0; ww < 8; ++ww) { s += redS[ww][tid]; qq += redQ[ww][tid]; }
    atomicAdd(&colSum[tid], s);
    atomicAdd(&colSq[tid], qq);
  }
}

// ---------------- BN2 apply (finalize folded): read bf16 sage, write fp32 d_out ----------------
__global__ __launch_bounds__(256) void k_bn_apply(const unsigned short* __restrict__ sageb,
                                                  float* __restrict__ out,
                                                  const float* __restrict__ colSum,
                                                  const float* __restrict__ colSq,
                                                  const float* __restrict__ g2,
                                                  const float* __restrict__ be2) {
  __shared__ __align__(16) float sa[HID], sb[HID];
  int tid = threadIdx.x;
  if (tid < HID) {
    float mu = colSum[tid] * (1.0f / NN);
    float var = fmaxf(colSq[tid] * (1.0f / NN) - mu * mu, 0.f);
    float a = g2[tid] * rsqrtf(var + BN_EPS);
    sa[tid] = a;
    sb[tid] = be2[tid] - mu * a;
  }
  __syncthreads();
  int i = blockIdx.x * 256 + tid;  // oct index: NN*16
  if (i >= NN * 16) return;
  int r = i >> 4, c8 = (i & 15) << 3;
  uint4 sv = *(const uint4*)(sageb + (size_t)r * HID + c8);
  float4 a0 = *(const float4*)(sa + c8);
  float4 a1 = *(const float4*)(sa + c8 + 4);
  float4 b0 = *(const float4*)(sb + c8);
  float4 b1 = *(const float4*)(sb + c8 + 4);
  float4 o0, o1;
  o0.x = fmaf(bflo(sv.x), a0.x, b0.x);
  o0.y = fmaf(bfhi(sv.x), a0.y, b0.y);
  o0.z = fmaf(bflo(sv.y), a0.z, b0.z);
  o0.w = fmaf(bfhi(sv.y), a0.w, b0.w);
  o1.x = fmaf(bflo(sv.z), a1.x, b1.x);
  o1.y = fmaf(bfhi(sv.z), a1.y, b1.y);
  o1.z = fmaf(bflo(sv.w), a1.z, b1.z);
  o1.w = fmaf(bfhi(sv.w), a1.w, b1.w);
  *(float4*)(out + (size_t)r * HID + c8) = o0;
  *(float4*)(out + (size_t)r * HID + c8 + 4) = o1;
}

extern "C" void kernel_launch(void* const* d_in, const int* in_sizes, int n_in,
                              void* d_out, int out_size, void* d_ws, size_t ws_size,
                              hipStream_t stream) {
  const float* x   = (const float*)d_in[0];
  const int*   ei  = (const int*)d_in[1];
  const float* W1  = (const float*)d_in[2];
  const float* b1  = (const float*)d_in[3];
  const float* g1  = (const float*)d_in[4];
  const float* be1 = (const float*)d_in[5];
  const float* Wl  = (const float*)d_in[6];
  const float* bl  = (const float*)d_in[7];
  const float* Wr  = (const float*)d_in[8];
  const float* g2  = (const float*)d_in[9];
  const float* be2 = (const float*)d_in[10];

  float* feat_out = (float*)d_out;                      // output 0: feat fp32
  float* out2     = (float*)d_out + (size_t)NN * HID;   // output 1: BN2(sage) fp32

  size_t off = 0;
  auto alloc = [&](size_t bytes) -> void* {
    void* p = (char*)d_ws + off;
    off += (bytes + 255) & ~(size_t)255;
    return p;
  };
  // stats + bcur first and contiguous: one small memset clears all
  float*          stats = (float*)alloc(4 * HID * 4);                    // 2048 B
  int*            bcur  = (int*)alloc((size_t)NBUK * 4);                 // directly after stats
  unsigned short* Abuf  = (unsigned short*)alloc((size_t)NN * K2 * 2);   // [NN][256] bf16: agg|feat
  unsigned char*  feat8 = (unsigned char*)alloc((size_t)NN * HID);       // fp8 e4m3 gather table
  unsigned short* sageb = (unsigned short*)alloc((size_t)NN * HID * 2);  // bf16 sage scratch
  unsigned int*   bbuf  = (unsigned int*)alloc((size_t)NBUK * BCAP * 4);
  float* colSum1 = stats;
  float* colSq1  = stats + HID;
  float* colSum2 = stats + 2 * HID;
  float* colSq2  = stats + 3 * HID;

  hipMemsetAsync(stats, 0, 4 * HID * 4 + (size_t)NBUK * 4, stream);
  k_prep_proj<<<NBB + NPRJ, 512, 0, stream>>>(ei, bcur, bbuf, x, W1, b1, Abuf, colSum1, colSq1);
  k_apply<<<(NN * 16 + 255) / 256, 256, 0, stream>>>(feat_out, colSum1, colSq1, g1, be1, Abuf, feat8);
  k_bucket_agg<<<NBUK, 512, 0, stream>>>(bbuf, bcur, feat8, Abuf);
  k_gemm<<<MT2, 512, 0, stream>>>(Abuf, Wl, Wr, bl, sageb, colSum2, colSq2);
  k_bn_apply<<<(NN * 16 + 255) / 256, 256, 0, stream>>>(sageb, out2, colSum2, colSq2, g2, be2);
}